// Round 14
// baseline (118.705 us; speedup 1.0000x reference)
//
#include <hip/hip_runtime.h>
#include <hip/hip_fp16.h>

#define CIN   96
#define MIDC  576
#define COUT  96
#define HW    784
#define W28   28
#define NX    4816896        /* 64*96*28*28  */

typedef __attribute__((ext_vector_type(8))) short short8;
typedef __attribute__((ext_vector_type(4))) float floatx4;

// ---------------- helpers ----------------

__device__ __forceinline__ float wave_max64(float v){
  #pragma unroll
  for(int i=32;i>=1;i>>=1) v = fmaxf(v, __shfl_xor(v, i, 64));
  return v;
}

__device__ __forceinline__ void block_max_atomic(float v, unsigned* dst){
  v = wave_max64(v);
  __shared__ float sm[8];
  int lane = threadIdx.x & 63, w = threadIdx.x >> 6;
  if(lane==0) sm[w] = v;
  __syncthreads();
  if(threadIdx.x==0){
    int nw = (blockDim.x + 63) >> 6;
    float m = sm[0];
    for(int i=1;i<nw;i++) m = fmaxf(m, sm[i]);
    atomicMax(dst, __float_as_uint(m));   // v>=0 always: uint order == float order
  }
}

// fake-quant (dequantized result), true division, round-half-even like jnp.round
__device__ __forceinline__ float fq(float x, float s){
  float q = rintf(x / s);
  q = fminf(fmaxf(q, -127.f), 127.f);
  return q * s;
}

// integer part of the quantization (true division)
__device__ __forceinline__ float qint(float x, float s){
  return fminf(fmaxf(rintf(x / s), -127.f), 127.f);
}

// integer part via reciprocal-mult (boundary flips ~1e-5, <= 1 intermediate step)
__device__ __forceinline__ float qintr(float x, float r){
  return fminf(fmaxf(rintf(x * r), -127.f), 127.f);
}

// fp32 (integer-valued, |v|<=127) -> bf16 bits, exact
__device__ __forceinline__ ushort f2bf(float f){
  return (ushort)(__float_as_uint(f) >> 16);
}

// ---------------- kernels ----------------

// Weight prep: 4 rows per block, one per wave (blocks 0..311); x absmax (blocks 312..823).
__global__ __launch_bounds__(256) void k_prep(
    const float* __restrict__ w1,const float* __restrict__ g1,const float* __restrict__ b1,const float* __restrict__ m1,const float* __restrict__ v1,
    const float* __restrict__ w2,const float* __restrict__ g2,const float* __restrict__ b2,const float* __restrict__ m2,const float* __restrict__ v2,
    const float* __restrict__ w3,const float* __restrict__ g3,const float* __restrict__ b3,const float* __restrict__ m3,const float* __restrict__ v3,
    ushort* __restrict__ qw1, float* __restrict__ sc1, float* __restrict__ bq1,
    float*  __restrict__ wq2, float* __restrict__ bq2,
    ushort* __restrict__ qw3, float* __restrict__ sc3, float* __restrict__ bq3,
    const float4* __restrict__ xv, unsigned* umax)
{
  int b = blockIdx.x, tid = threadIdx.x;
  if(b >= 312){                                   // x absmax, 512 blocks x 256 thr
    float m = 0.f;
    for(int i = (b-312)*256 + tid; i < NX/4; i += 512*256){
      float4 v = xv[i];
      m = fmaxf(m, fmaxf(fmaxf(fabsf(v.x), fabsf(v.y)), fmaxf(fabsf(v.z), fabsf(v.w))));
    }
    block_max_atomic(m, umax);
    return;
  }
  int w = tid >> 6, lane = tid & 63;
  if(b < 144){                                    // conv1 weights: row o, 96 elems
    int o = b*4 + w;
    float f = g1[o] / sqrtf(v1[o] + 1e-5f);
    float x0 = w1[o*CIN + lane] * f;
    float x1 = (lane < 32) ? w1[o*CIN + 64 + lane] * f : 0.f;
    float m = wave_max64(fmaxf(fabsf(x0), fabsf(x1)));
    float s = m / 127.f + 1e-8f;
    qw1[o*CIN + lane] = f2bf(qint(x0, s));
    if(lane < 32) qw1[o*CIN + 64 + lane] = f2bf(qint(x1, s));
    if(lane==0){ sc1[o] = s; bq1[o] = b1[o] - m1[o]*f; }
  } else if(b < 288){                             // depthwise weights: channel c, 9 elems
    int c = (b-144)*4 + w;
    float f = g2[c] / sqrtf(v2[c] + 1e-5f);
    float x0 = (lane < 9) ? w2[c*9 + lane] * f : 0.f;
    float m = wave_max64(fabsf(x0));
    float s = m / 127.f + 1e-8f;
    if(lane < 9) wq2[c*9 + lane] = fq(x0, s);
    if(lane==0) bq2[c] = b2[c] - m2[c]*f;
  } else {                                        // conv3 weights: row o, 576 elems (k-contiguous)
    int o = (b-288)*4 + w;
    float f = g3[o] / sqrtf(v3[o] + 1e-5f);
    float xs[9]; float m = 0.f;
    #pragma unroll
    for(int k=0;k<9;k++){ int c = lane + 64*k; xs[k] = w3[o*MIDC + c] * f; m = fmaxf(m, fabsf(xs[k])); }
    m = wave_max64(m);
    float s = m / 127.f + 1e-8f;
    #pragma unroll
    for(int k=0;k<9;k++){ int c = lane + 64*k; qw3[o*MIDC + c] = f2bf(qint(xs[k], s)); }
    if(lane==0){ sc3[o] = s; bq3[o] = b3[o] - m3[o]*f; }
  }
}

// FUSED x-quantize + 1x1 conv 96->576 via MFMA. grid (64 n, 14 pc) x 384 thr (6 waves).
// Stages x fp32 -> bf16-int B-tile [12 cb][64 px][8 c8] in LDS (px 56..63 garbage:
// MFMA col c depends only on B col c, and px>=56 outputs are store-masked).
__global__ __launch_bounds__(384) void k_conv1f(const float* __restrict__ x,
    const ushort* __restrict__ qw1, const float* __restrict__ sc1, const float* __restrict__ bq1,
    unsigned* umax, __half* __restrict__ y1T)
{
  __shared__ ushort bt[12*64*8];                 // 12288 B
  int n = blockIdx.x, pc = blockIdx.y, tid = threadIdx.x;
  int w = tid >> 6, l = tid & 63;
  int lhi = l >> 4, llo = l & 15;
  int p0 = pc*56;
  float s0 = __uint_as_float(umax[0])/127.f + 1e-8f;
  float r0 = 1.f/s0;
  for(int i = tid; i < 96*14; i += 384){         // stage + quantize x
    int c = i/14, q = i - c*14;
    float4 v = *(const float4*)(x + (size_t)(n*CIN + c)*HW + p0 + q*4);
    int cb = c >> 3, c8 = c & 7;
    ushort* bp = bt + (cb*64 + q*4)*8 + c8;
    bp[0]  = f2bf(qintr(v.x, r0));
    bp[8]  = f2bf(qintr(v.y, r0));
    bp[16] = f2bf(qintr(v.z, r0));
    bp[24] = f2bf(qintr(v.w, r0));
  }
  __syncthreads();
  float tmax = 0.f;
  for(int mt=0; mt<6; mt++){
    int m0 = mt*96 + w*16;
    short8 a[3];
    #pragma unroll
    for(int ks=0; ks<3; ks++)
      a[ks] = *(const short8*)(qw1 + (m0 + llo)*CIN + ks*32 + lhi*8);
    float scf[4], bf[4];
    #pragma unroll
    for(int r=0;r<4;r++){ int o = m0 + lhi*4 + r; scf[r] = s0*sc1[o]; bf[r] = bq1[o]; }
    floatx4 acc[4];
    #pragma unroll
    for(int f=0;f<4;f++) acc[f] = (floatx4){0.f,0.f,0.f,0.f};
    #pragma unroll
    for(int ks=0; ks<3; ks++){
      #pragma unroll
      for(int f=0; f<4; f++){
        const short8 b = *(const short8*)(bt + ((ks*4 + lhi)*64 + f*16 + llo)*8);
        acc[f] = __builtin_amdgcn_mfma_f32_16x16x32_bf16(a[ks], b, acc[f], 0, 0, 0);
      }
    }
    int cgbase = (m0 >> 3) + (lhi >> 1);
    int c8base = (lhi & 1) * 4;
    #pragma unroll
    for(int f=0; f<4; f++){
      if(f*16 + llo < 56){
        uint pk0 = 0, pk1 = 0;
        #pragma unroll
        for(int r=0;r<4;r++){
          float v = fmaf(acc[f][r], scf[r], bf[r]);
          v = fminf(fmaxf(v, 0.f), 6.f);
          tmax = fmaxf(tmax, v);
          uint hb = (uint)__half_as_ushort(__float2half(v));
          if(r==0) pk0 = hb;        else if(r==1) pk0 |= hb<<16;
          else if(r==2) pk1 = hb;   else pk1 |= hb<<16;
        }
        uint2 pk; pk.x = pk0; pk.y = pk1;
        *(uint2*)((ushort*)y1T + ((size_t)(n*72 + cgbase)*HW + p0 + f*16 + llo)*8 + c8base) = pk;
      }
    }
  }
  block_max_atomic(tmax, umax + 1);
}

// depthwise 3x3 pad1 + ReLU6 + inline max. Blocked in/out [n][72][784][8] fp16.
// Double-buffered 4-tile pipeline; compute phase: thread owns a 4-px row quad,
// sharing the 3x6 tap window (halves LDS loads + f16 unpacks vs per-px).
// Per-output fma chain order (dy->dx) identical to prior rounds => bitwise-same y2T.
__global__ __launch_bounds__(256) void k_conv2(const __half* __restrict__ y1T,
    const float* __restrict__ wq2, const float* __restrict__ bq2,
    unsigned* umax, __half* __restrict__ y2T)
{
  __shared__ ushort tile[2][30*30*8];            // 2 x 14400 B, zero borders
  int cg = blockIdx.x >> 4, nb = (blockIdx.x & 15) << 2;
  int tid = threadIdx.x;
  float s1 = __uint_as_float(umax[1])/127.f + 1e-8f;
  float r1 = 1.f/s1;
  const float* wc = wq2 + cg*72;                 // [c8][9], wave-uniform
  const float* bc = bq2 + cg*8;
  float tmax = 0.f;

  // border zeros, both buffers (never overwritten)
  #pragma unroll
  for(int bfi=0; bfi<2; bfi++){
    uint4* t4z = (uint4*)tile[bfi];
    if(tid < 116){
      int h, w;
      if(tid < 30){ h = 0; w = tid; }
      else if(tid < 60){ h = 29; w = tid - 30; }
      else if(tid < 88){ h = tid - 59; w = 0; }
      else { h = tid - 87; w = 29; }
      t4z[h*30 + w] = (uint4){0u,0u,0u,0u};
    }
  }

  uint4 ld[4];
  // preload + stage tile 0 into buf 0
  {
    const uint4* g4 = (const uint4*)(y1T + (size_t)(nb*72 + cg)*HW*8);
    #pragma unroll
    for(int i=0;i<4;i++){ int p = tid + i*256; if(p < HW) ld[i] = g4[p]; }
    uint4* t4 = (uint4*)tile[0];
    #pragma unroll
    for(int i=0;i<4;i++){
      int p = tid + i*256;
      if(p < HW){
        int h = p/W28, w = p - h*W28;
        uint rw[4] = {ld[i].x, ld[i].y, ld[i].z, ld[i].w};
        uint pk[4];
        #pragma unroll
        for(int j=0;j<4;j++){
          float lo = __half2float(__ushort_as_half((ushort)(rw[j] & 0xffffu)));
          float hi = __half2float(__ushort_as_half((ushort)(rw[j] >> 16)));
          uint qlo = (uint)__half_as_ushort(__float2half(rintf(lo * r1)));
          uint qhi = (uint)__half_as_ushort(__float2half(rintf(hi * r1)));
          pk[j] = (qhi << 16) | qlo;
        }
        t4[(h+1)*30 + (w+1)] = (uint4){pk[0], pk[1], pk[2], pk[3]};
      }
    }
  }

  int cur = 0;
  for(int it=0; it<4; it++){
    int n = nb + it;
    if(it < 3){                                  // issue next tile's loads now
      const uint4* g4 = (const uint4*)(y1T + (size_t)((n+1)*72 + cg)*HW*8);
      #pragma unroll
      for(int i=0;i<4;i++){ int p = tid + i*256; if(p < HW) ld[i] = g4[p]; }
    }
    __syncthreads();                             // publish buf[cur] (and borders)
    // compute from buf[cur]: thread = 4-px row quad (196 active)
    const uint4* t4 = (const uint4*)tile[cur];
    uint4* o4 = (uint4*)(y2T + (size_t)(n*72 + cg)*HW*8);
    if(tid < 196){
      int pq = tid*4;
      int h = pq/W28, w0 = pq - h*W28;           // w0 in {0,4,...,24}; quad stays in-row
      float acc[4][8];
      #pragma unroll
      for(int k=0;k<4;k++)
        #pragma unroll
        for(int c=0;c<8;c++) acc[k][c] = 0.f;
      #pragma unroll
      for(int dy=0; dy<3; dy++){
        uint4 t[6];
        #pragma unroll
        for(int j=0;j<6;j++) t[j] = t4[(h+dy)*30 + (w0+j)];
        #pragma unroll
        for(int j=0;j<6;j++){
          float f8[8];
          uint rw[4] = {t[j].x, t[j].y, t[j].z, t[j].w};
          #pragma unroll
          for(int u=0;u<4;u++){
            f8[2*u]   = __half2float(__ushort_as_half((ushort)(rw[u] & 0xffffu)));
            f8[2*u+1] = __half2float(__ushort_as_half((ushort)(rw[u] >> 16)));
          }
          int klo = (j >= 3) ? (j-2) : 0;
          int khi = (j < 4) ? j : 3;
          #pragma unroll
          for(int k=0;k<4;k++){
            if(k >= klo && k <= khi){
              int dx = j - k;
              #pragma unroll
              for(int c=0;c<8;c++)
                acc[k][c] = fmaf(f8[c], wc[c*9 + dy*3 + dx], acc[k][c]);
            }
          }
        }
      }
      #pragma unroll
      for(int k=0;k<4;k++){
        uint pk[4];
        #pragma unroll
        for(int j=0;j<4;j++){
          float o0 = fmaf(acc[k][2*j],   s1, bc[2*j]);
          float o1 = fmaf(acc[k][2*j+1], s1, bc[2*j+1]);
          o0 = fminf(fmaxf(o0, 0.f), 6.f);
          o1 = fminf(fmaxf(o1, 0.f), 6.f);
          tmax = fmaxf(tmax, fmaxf(o0, o1));
          uint lo = (uint)__half_as_ushort(__float2half(o0));
          uint hi = (uint)__half_as_ushort(__float2half(o1));
          pk[j] = (hi << 16) | lo;
        }
        o4[pq + k] = (uint4){pk[0], pk[1], pk[2], pk[3]};
      }
    }
    // stage next tile into the other buffer (its last readers passed the barrier above)
    if(it < 3){
      uint4* t4n = (uint4*)tile[cur ^ 1];
      #pragma unroll
      for(int i=0;i<4;i++){
        int p = tid + i*256;
        if(p < HW){
          int h = p/W28, w = p - h*W28;
          uint rw[4] = {ld[i].x, ld[i].y, ld[i].z, ld[i].w};
          uint pk[4];
          #pragma unroll
          for(int j=0;j<4;j++){
            float lo = __half2float(__ushort_as_half((ushort)(rw[j] & 0xffffu)));
            float hi = __half2float(__ushort_as_half((ushort)(rw[j] >> 16)));
            uint qlo = (uint)__half_as_ushort(__float2half(rintf(lo * r1)));
            uint qhi = (uint)__half_as_ushort(__float2half(rintf(hi * r1)));
            pk[j] = (qhi << 16) | qlo;
          }
          t4n[(h+1)*30 + (w+1)] = (uint4){pk[0], pk[1], pk[2], pk[3]};
        }
      }
    }
    cur ^= 1;
  }
  block_max_atomic(tmax, umax + 2);
}

// FUSED quantize + 1x1 conv 576->96 via MFMA + bias + identity.
// grid (64 n, 14 pc) x 384 thr. K in 3 chunks of 192; chunk k+1's global loads are
// issued right after chunk k's LDS write (async-STAGE), reciprocal quantize.
// px 56..63 of the B-tile are garbage (uninitialized) - harmless: MFMA col c depends
// only on B col c, and those output px are store-masked.
__global__ __launch_bounds__(384) void k_conv3(const __half* __restrict__ y2T,
    const ushort* __restrict__ qw3, const float* __restrict__ sc3, const float* __restrict__ bq3,
    const float* __restrict__ x, unsigned* umax, float* __restrict__ out)
{
  __shared__ ushort lds[24*64*8];                // 24576 B (stride-64 addressing)
  int n = blockIdx.x, pc = blockIdx.y, tid = threadIdx.x;
  int w = tid >> 6, l = tid & 63;
  int lhi = l >> 4, llo = l & 15;
  int m0 = w*16;
  int p0 = pc*56;
  float s2 = __uint_as_float(umax[2])/127.f + 1e-8f;
  float r2 = 1.f/s2;
  uint4* l4 = (uint4*)lds;
  float scf[4], bf[4];
  #pragma unroll
  for(int r=0;r<4;r++){ int o = m0 + lhi*4 + r; scf[r] = s2*sc3[o]; bf[r] = bq3[o]; }
  floatx4 acc[4];
  #pragma unroll
  for(int f=0;f<4;f++) acc[f] = (floatx4){0.f,0.f,0.f,0.f};

  uint4 ld[4];
  // prefetch chunk 0
  #pragma unroll
  for(int i=0;i<4;i++){
    int idx = tid + i*384;
    if(idx < 24*56){
      int cl = idx/56, r = idx - cl*56;
      ld[i] = *(const uint4*)((const ushort*)y2T + ((size_t)(n*72 + cl)*HW + p0 + r)*8);
    }
  }
  for(int ck=0; ck<3; ck++){
    if(ck > 0) __syncthreads();                  // prev chunk's MFMA readers done
    // write regs -> LDS, quantizing (reciprocal-mult; q in [0,127])
    #pragma unroll
    for(int i=0;i<4;i++){
      int idx = tid + i*384;
      if(idx < 24*56){
        int cl = idx/56, r = idx - cl*56;
        uint rw[4] = {ld[i].x, ld[i].y, ld[i].z, ld[i].w};
        uint pk[4];
        #pragma unroll
        for(int j=0;j<4;j++){
          float lo = __half2float(__ushort_as_half((ushort)(rw[j] & 0xffffu)));
          float hi = __half2float(__ushort_as_half((ushort)(rw[j] >> 16)));
          uint qlo = (uint)f2bf(rintf(lo * r2));
          uint qhi = (uint)f2bf(rintf(hi * r2));
          pk[j] = (qhi << 16) | qlo;
        }
        l4[cl*64 + r] = (uint4){pk[0], pk[1], pk[2], pk[3]};
      }
    }
    if(ck < 2){                                  // issue next chunk's loads NOW
      #pragma unroll
      for(int i=0;i<4;i++){
        int idx = tid + i*384;
        if(idx < 24*56){
          int cl = idx/56, r = idx - cl*56;
          ld[i] = *(const uint4*)((const ushort*)y2T + ((size_t)(n*72 + (ck+1)*24 + cl)*HW + p0 + r)*8);
        }
      }
    }
    __syncthreads();                             // LDS visible
    #pragma unroll
    for(int ks=0; ks<6; ks++){
      const short8 a = *(const short8*)(qw3 + (m0 + llo)*MIDC + ck*192 + ks*32 + lhi*8);
      #pragma unroll
      for(int f=0; f<4; f++){
        const short8 b = *(const short8*)(lds + ((ks*4 + lhi)*64 + f*16 + llo)*8);
        acc[f] = __builtin_amdgcn_mfma_f32_16x16x32_bf16(a, b, acc[f], 0, 0, 0);
      }
    }
  }
  float tmax = 0.f;
  #pragma unroll
  for(int f=0; f<4; f++){
    if(f*16 + llo < 56){
      #pragma unroll
      for(int r=0;r<4;r++){
        size_t idx = (size_t)(n*COUT + m0 + lhi*4 + r)*HW + p0 + f*16 + llo;
        float v = fmaf(acc[f][r], scf[r], bf[r]) + x[idx];
        tmax = fmaxf(tmax, fabsf(v));
        out[idx] = v;
      }
    }
  }
  block_max_atomic(tmax, umax + 3);
}

// final per-tensor fake-quant of out (in place) + write scale. TRUE division kept here.
__global__ void k_finalq(float* __restrict__ out, const unsigned* __restrict__ umax, float* __restrict__ sf){
  int i = blockIdx.x*256 + threadIdx.x;          // exactly NX/4 threads
  float s3 = __uint_as_float(umax[3]) / 127.f + 1e-8f;
  float4* o4 = (float4*)out;
  float4 v = o4[i];
  v.x = fq(v.x, s3); v.y = fq(v.y, s3); v.z = fq(v.z, s3); v.w = fq(v.w, s3);
  o4[i] = v;
  if(i == 0) *sf = s3;
}

// ---------------- launch ----------------

extern "C" void kernel_launch(void* const* d_in, const int* in_sizes, int n_in,
                              void* d_out, int out_size, void* d_ws, size_t ws_size,
                              hipStream_t stream)
{
  const float* x  = (const float*)d_in[0];
  const float* w1 = (const float*)d_in[1];
  const float* g1 = (const float*)d_in[2];
  const float* b1 = (const float*)d_in[3];
  const float* m1 = (const float*)d_in[4];
  const float* v1 = (const float*)d_in[5];
  const float* w2 = (const float*)d_in[6];
  const float* g2 = (const float*)d_in[7];
  const float* b2 = (const float*)d_in[8];
  const float* m2 = (const float*)d_in[9];
  const float* v2 = (const float*)d_in[10];
  const float* w3 = (const float*)d_in[11];
  const float* g3 = (const float*)d_in[12];
  const float* b3 = (const float*)d_in[13];
  const float* m3 = (const float*)d_in[14];
  const float* v3 = (const float*)d_in[15];

  char* ws = (char*)d_ws;
  unsigned* umax = (unsigned*)(ws + 0);
  float* sc1  = (float*)(ws + 256);
  float* bq1  = (float*)(ws + 2560);
  float* bq2  = (float*)(ws + 4864);
  float* wq2  = (float*)(ws + 7168);
  float* sc3  = (float*)(ws + 27904);
  float* bq3  = (float*)(ws + 28288);
  ushort* qw1 = (ushort*)(ws + 28672);
  ushort* qw3 = (ushort*)(ws + 139264);
  __half* y1T = (__half*)(ws + 9883648);         // fp16 blocked, 57.8 MB
  __half* y2T = (__half*)(ws + 67686400);        // fp16 blocked, 57.8 MB

  float* outp = (float*)d_out;

  hipMemsetAsync(umax, 0, 16, stream);
  k_prep<<<824, 256, 0, stream>>>(w1,g1,b1,m1,v1, w2,g2,b2,m2,v2, w3,g3,b3,m3,v3,
                                  qw1,sc1,bq1, wq2,bq2, qw3,sc3,bq3,
                                  (const float4*)x, umax);
  k_conv1f<<<dim3(64,14), 384, 0, stream>>>(x, qw1, sc1, bq1, umax, y1T);
  k_conv2<<<1152, 256, 0, stream>>>(y1T, wq2, bq2, umax, y2T);
  k_conv3<<<dim3(64,14), 384, 0, stream>>>(y2T, qw3, sc3, bq3, x, umax, outp);
  k_finalq<<<NX/4/256, 256, 0, stream>>>(outp, umax, outp + NX);
}

// Round 15
// 117.576 us; speedup vs baseline: 1.0096x; 1.0096x over previous
//
#include <hip/hip_runtime.h>
#include <hip/hip_fp16.h>

#define CIN   96
#define MIDC  576
#define COUT  96
#define HW    784
#define W28   28
#define NX    4816896        /* 64*96*28*28  */

typedef __attribute__((ext_vector_type(8))) short short8;
typedef __attribute__((ext_vector_type(4))) float floatx4;

// ---------------- helpers ----------------

__device__ __forceinline__ float wave_max64(float v){
  #pragma unroll
  for(int i=32;i>=1;i>>=1) v = fmaxf(v, __shfl_xor(v, i, 64));
  return v;
}

__device__ __forceinline__ void block_max_atomic(float v, unsigned* dst){
  v = wave_max64(v);
  __shared__ float sm[8];
  int lane = threadIdx.x & 63, w = threadIdx.x >> 6;
  if(lane==0) sm[w] = v;
  __syncthreads();
  if(threadIdx.x==0){
    int nw = (blockDim.x + 63) >> 6;
    float m = sm[0];
    for(int i=1;i<nw;i++) m = fmaxf(m, sm[i]);
    atomicMax(dst, __float_as_uint(m));   // v>=0 always: uint order == float order
  }
}

// fake-quant (dequantized result), true division, round-half-even like jnp.round
__device__ __forceinline__ float fq(float x, float s){
  float q = rintf(x / s);
  q = fminf(fmaxf(q, -127.f), 127.f);
  return q * s;
}

// integer part of the quantization (true division)
__device__ __forceinline__ float qint(float x, float s){
  return fminf(fmaxf(rintf(x / s), -127.f), 127.f);
}

// integer part via reciprocal-mult (boundary flips ~1e-5, <= 1 intermediate step)
__device__ __forceinline__ float qintr(float x, float r){
  return fminf(fmaxf(rintf(x * r), -127.f), 127.f);
}

// fp32 (integer-valued, |v|<=127) -> bf16 bits, exact
__device__ __forceinline__ ushort f2bf(float f){
  return (ushort)(__float_as_uint(f) >> 16);
}

// ---------------- kernels ----------------

// Weight prep: 4 rows per block, one per wave (blocks 0..311); x absmax (blocks 312..823).
__global__ __launch_bounds__(256) void k_prep(
    const float* __restrict__ w1,const float* __restrict__ g1,const float* __restrict__ b1,const float* __restrict__ m1,const float* __restrict__ v1,
    const float* __restrict__ w2,const float* __restrict__ g2,const float* __restrict__ b2,const float* __restrict__ m2,const float* __restrict__ v2,
    const float* __restrict__ w3,const float* __restrict__ g3,const float* __restrict__ b3,const float* __restrict__ m3,const float* __restrict__ v3,
    ushort* __restrict__ qw1, float* __restrict__ sc1, float* __restrict__ bq1,
    float*  __restrict__ wq2, float* __restrict__ bq2,
    ushort* __restrict__ qw3, float* __restrict__ sc3, float* __restrict__ bq3,
    const float4* __restrict__ xv, unsigned* umax)
{
  int b = blockIdx.x, tid = threadIdx.x;
  if(b >= 312){                                   // x absmax, 512 blocks x 256 thr
    float m = 0.f;
    for(int i = (b-312)*256 + tid; i < NX/4; i += 512*256){
      float4 v = xv[i];
      m = fmaxf(m, fmaxf(fmaxf(fabsf(v.x), fabsf(v.y)), fmaxf(fabsf(v.z), fabsf(v.w))));
    }
    block_max_atomic(m, umax);
    return;
  }
  int w = tid >> 6, lane = tid & 63;
  if(b < 144){                                    // conv1 weights: row o, 96 elems
    int o = b*4 + w;
    float f = g1[o] / sqrtf(v1[o] + 1e-5f);
    float x0 = w1[o*CIN + lane] * f;
    float x1 = (lane < 32) ? w1[o*CIN + 64 + lane] * f : 0.f;
    float m = wave_max64(fmaxf(fabsf(x0), fabsf(x1)));
    float s = m / 127.f + 1e-8f;
    qw1[o*CIN + lane] = f2bf(qint(x0, s));
    if(lane < 32) qw1[o*CIN + 64 + lane] = f2bf(qint(x1, s));
    if(lane==0){ sc1[o] = s; bq1[o] = b1[o] - m1[o]*f; }
  } else if(b < 288){                             // depthwise weights: channel c, 9 elems
    int c = (b-144)*4 + w;
    float f = g2[c] / sqrtf(v2[c] + 1e-5f);
    float x0 = (lane < 9) ? w2[c*9 + lane] * f : 0.f;
    float m = wave_max64(fabsf(x0));
    float s = m / 127.f + 1e-8f;
    if(lane < 9) wq2[c*9 + lane] = fq(x0, s);
    if(lane==0) bq2[c] = b2[c] - m2[c]*f;
  } else {                                        // conv3 weights: row o, 576 elems (k-contiguous)
    int o = (b-288)*4 + w;
    float f = g3[o] / sqrtf(v3[o] + 1e-5f);
    float xs[9]; float m = 0.f;
    #pragma unroll
    for(int k=0;k<9;k++){ int c = lane + 64*k; xs[k] = w3[o*MIDC + c] * f; m = fmaxf(m, fabsf(xs[k])); }
    m = wave_max64(m);
    float s = m / 127.f + 1e-8f;
    #pragma unroll
    for(int k=0;k<9;k++){ int c = lane + 64*k; qw3[o*MIDC + c] = f2bf(qint(xs[k], s)); }
    if(lane==0){ sc3[o] = s; bq3[o] = b3[o] - m3[o]*f; }
  }
}

// FUSED x-quantize + 1x1 conv 96->576 via MFMA. grid (64 n, 14 pc) x 384 thr (6 waves).
// Head-of-kernel latency fix: ALL x loads are issued to registers BEFORE the s0
// (umax) read is consumed; quantize pass then writes LDS. Bitwise-identical math.
__global__ __launch_bounds__(384) void k_conv1f(const float* __restrict__ x,
    const ushort* __restrict__ qw1, const float* __restrict__ sc1, const float* __restrict__ bq1,
    unsigned* umax, __half* __restrict__ y1T)
{
  __shared__ ushort bt[12*64*8];                 // 12288 B
  int n = blockIdx.x, pc = blockIdx.y, tid = threadIdx.x;
  int w = tid >> 6, l = tid & 63;
  int lhi = l >> 4, llo = l & 15;
  int p0 = pc*56;
  // pass 1: issue loads (addresses independent of s0)
  float4 vld[4]; int cc[4], qq[4];
  #pragma unroll
  for(int k=0;k<4;k++){
    int i = tid + k*384;
    if(i < 96*14){
      int c = i/14, q = i - c*14;
      cc[k] = c; qq[k] = q;
      vld[k] = *(const float4*)(x + (size_t)(n*CIN + c)*HW + p0 + q*4);
    }
  }
  float s0 = __uint_as_float(umax[0])/127.f + 1e-8f;
  float r0 = 1.f/s0;
  // pass 2: quantize + write LDS
  #pragma unroll
  for(int k=0;k<4;k++){
    int i = tid + k*384;
    if(i < 96*14){
      int cb = cc[k] >> 3, c8 = cc[k] & 7;
      ushort* bp = bt + (cb*64 + qq[k]*4)*8 + c8;
      bp[0]  = f2bf(qintr(vld[k].x, r0));
      bp[8]  = f2bf(qintr(vld[k].y, r0));
      bp[16] = f2bf(qintr(vld[k].z, r0));
      bp[24] = f2bf(qintr(vld[k].w, r0));
    }
  }
  __syncthreads();
  float tmax = 0.f;
  for(int mt=0; mt<6; mt++){
    int m0 = mt*96 + w*16;
    short8 a[3];
    #pragma unroll
    for(int ks=0; ks<3; ks++)
      a[ks] = *(const short8*)(qw1 + (m0 + llo)*CIN + ks*32 + lhi*8);
    float scf[4], bf[4];
    #pragma unroll
    for(int r=0;r<4;r++){ int o = m0 + lhi*4 + r; scf[r] = s0*sc1[o]; bf[r] = bq1[o]; }
    floatx4 acc[4];
    #pragma unroll
    for(int f=0;f<4;f++) acc[f] = (floatx4){0.f,0.f,0.f,0.f};
    #pragma unroll
    for(int ks=0; ks<3; ks++){
      #pragma unroll
      for(int f=0; f<4; f++){
        const short8 b = *(const short8*)(bt + ((ks*4 + lhi)*64 + f*16 + llo)*8);
        acc[f] = __builtin_amdgcn_mfma_f32_16x16x32_bf16(a[ks], b, acc[f], 0, 0, 0);
      }
    }
    int cgbase = (m0 >> 3) + (lhi >> 1);
    int c8base = (lhi & 1) * 4;
    #pragma unroll
    for(int f=0; f<4; f++){
      if(f*16 + llo < 56){
        uint pk0 = 0, pk1 = 0;
        #pragma unroll
        for(int r=0;r<4;r++){
          float v = fmaf(acc[f][r], scf[r], bf[r]);
          v = fminf(fmaxf(v, 0.f), 6.f);
          tmax = fmaxf(tmax, v);
          uint hb = (uint)__half_as_ushort(__float2half(v));
          if(r==0) pk0 = hb;        else if(r==1) pk0 |= hb<<16;
          else if(r==2) pk1 = hb;   else pk1 |= hb<<16;
        }
        uint2 pk; pk.x = pk0; pk.y = pk1;
        *(uint2*)((ushort*)y1T + ((size_t)(n*72 + cgbase)*HW + p0 + f*16 + llo)*8 + c8base) = pk;
      }
    }
  }
  block_max_atomic(tmax, umax + 1);
}

// depthwise 3x3 pad1 + ReLU6 + inline max. Blocked in/out [n][72][784][8] fp16.
// Double-buffered 4-tile pipeline; tile-0 loads issued BEFORE the s1 read.
__global__ __launch_bounds__(256) void k_conv2(const __half* __restrict__ y1T,
    const float* __restrict__ wq2, const float* __restrict__ bq2,
    unsigned* umax, __half* __restrict__ y2T)
{
  __shared__ ushort tile[2][30*30*8];            // 2 x 14400 B, zero borders
  int cg = blockIdx.x >> 4, nb = (blockIdx.x & 15) << 2;
  int tid = threadIdx.x;

  uint4 ld[4];
  // issue tile-0 loads FIRST (addresses independent of s1)
  {
    const uint4* g4 = (const uint4*)(y1T + (size_t)(nb*72 + cg)*HW*8);
    #pragma unroll
    for(int i=0;i<4;i++){ int p = tid + i*256; if(p < HW) ld[i] = g4[p]; }
  }
  // border zeros, both buffers (LDS, independent of loads)
  #pragma unroll
  for(int bfi=0; bfi<2; bfi++){
    uint4* t4z = (uint4*)tile[bfi];
    if(tid < 116){
      int h, w;
      if(tid < 30){ h = 0; w = tid; }
      else if(tid < 60){ h = 29; w = tid - 30; }
      else if(tid < 88){ h = tid - 59; w = 0; }
      else { h = tid - 87; w = 29; }
      t4z[h*30 + w] = (uint4){0u,0u,0u,0u};
    }
  }
  float s1 = __uint_as_float(umax[1])/127.f + 1e-8f;
  float r1 = 1.f/s1;
  const float* wc = wq2 + cg*72;                 // [c8][9], wave-uniform
  const float* bc = bq2 + cg*8;
  float tmax = 0.f;

  // stage tile 0 into buf 0
  {
    uint4* t4 = (uint4*)tile[0];
    #pragma unroll
    for(int i=0;i<4;i++){
      int p = tid + i*256;
      if(p < HW){
        int h = p/W28, w = p - h*W28;
        uint rw[4] = {ld[i].x, ld[i].y, ld[i].z, ld[i].w};
        uint pk[4];
        #pragma unroll
        for(int j=0;j<4;j++){
          float lo = __half2float(__ushort_as_half((ushort)(rw[j] & 0xffffu)));
          float hi = __half2float(__ushort_as_half((ushort)(rw[j] >> 16)));
          uint qlo = (uint)__half_as_ushort(__float2half(rintf(lo * r1)));
          uint qhi = (uint)__half_as_ushort(__float2half(rintf(hi * r1)));
          pk[j] = (qhi << 16) | qlo;
        }
        t4[(h+1)*30 + (w+1)] = (uint4){pk[0], pk[1], pk[2], pk[3]};
      }
    }
  }

  int cur = 0;
  for(int it=0; it<4; it++){
    int n = nb + it;
    if(it < 3){                                  // issue next tile's loads now
      const uint4* g4 = (const uint4*)(y1T + (size_t)((n+1)*72 + cg)*HW*8);
      #pragma unroll
      for(int i=0;i<4;i++){ int p = tid + i*256; if(p < HW) ld[i] = g4[p]; }
    }
    __syncthreads();                             // publish buf[cur] (and borders)
    // compute from buf[cur]: thread = 4-px row quad (196 active)
    const uint4* t4 = (const uint4*)tile[cur];
    uint4* o4 = (uint4*)(y2T + (size_t)(n*72 + cg)*HW*8);
    if(tid < 196){
      int pq = tid*4;
      int h = pq/W28, w0 = pq - h*W28;           // w0 in {0,4,...,24}; quad stays in-row
      float acc[4][8];
      #pragma unroll
      for(int k=0;k<4;k++)
        #pragma unroll
        for(int c=0;c<8;c++) acc[k][c] = 0.f;
      #pragma unroll
      for(int dy=0; dy<3; dy++){
        uint4 t[6];
        #pragma unroll
        for(int j=0;j<6;j++) t[j] = t4[(h+dy)*30 + (w0+j)];
        #pragma unroll
        for(int j=0;j<6;j++){
          float f8[8];
          uint rw[4] = {t[j].x, t[j].y, t[j].z, t[j].w};
          #pragma unroll
          for(int u=0;u<4;u++){
            f8[2*u]   = __half2float(__ushort_as_half((ushort)(rw[u] & 0xffffu)));
            f8[2*u+1] = __half2float(__ushort_as_half((ushort)(rw[u] >> 16)));
          }
          int klo = (j >= 3) ? (j-2) : 0;
          int khi = (j < 4) ? j : 3;
          #pragma unroll
          for(int k=0;k<4;k++){
            if(k >= klo && k <= khi){
              int dx = j - k;
              #pragma unroll
              for(int c=0;c<8;c++)
                acc[k][c] = fmaf(f8[c], wc[c*9 + dy*3 + dx], acc[k][c]);
            }
          }
        }
      }
      #pragma unroll
      for(int k=0;k<4;k++){
        uint pk[4];
        #pragma unroll
        for(int j=0;j<4;j++){
          float o0 = fmaf(acc[k][2*j],   s1, bc[2*j]);
          float o1 = fmaf(acc[k][2*j+1], s1, bc[2*j+1]);
          o0 = fminf(fmaxf(o0, 0.f), 6.f);
          o1 = fminf(fmaxf(o1, 0.f), 6.f);
          tmax = fmaxf(tmax, fmaxf(o0, o1));
          uint lo = (uint)__half_as_ushort(__float2half(o0));
          uint hi = (uint)__half_as_ushort(__float2half(o1));
          pk[j] = (hi << 16) | lo;
        }
        o4[pq + k] = (uint4){pk[0], pk[1], pk[2], pk[3]};
      }
    }
    // stage next tile into the other buffer (its last readers passed the barrier above)
    if(it < 3){
      uint4* t4n = (uint4*)tile[cur ^ 1];
      #pragma unroll
      for(int i=0;i<4;i++){
        int p = tid + i*256;
        if(p < HW){
          int h = p/W28, w = p - h*W28;
          uint rw[4] = {ld[i].x, ld[i].y, ld[i].z, ld[i].w};
          uint pk[4];
          #pragma unroll
          for(int j=0;j<4;j++){
            float lo = __half2float(__ushort_as_half((ushort)(rw[j] & 0xffffu)));
            float hi = __half2float(__ushort_as_half((ushort)(rw[j] >> 16)));
            uint qlo = (uint)__half_as_ushort(__float2half(rintf(lo * r1)));
            uint qhi = (uint)__half_as_ushort(__float2half(rintf(hi * r1)));
            pk[j] = (qhi << 16) | qlo;
          }
          t4n[(h+1)*30 + (w+1)] = (uint4){pk[0], pk[1], pk[2], pk[3]};
        }
      }
    }
    cur ^= 1;
  }
  block_max_atomic(tmax, umax + 2);
}

// FUSED quantize + 1x1 conv 576->96 via MFMA + bias + identity.
// grid (64 n, 14 pc) x 384 thr. K in 3 chunks of 192; chunk-0 loads issued BEFORE
// the s2 read; chunk k+1's loads issued right after chunk k's LDS write.
// px 56..63 of the B-tile are garbage - harmless (outputs store-masked).
__global__ __launch_bounds__(384) void k_conv3(const __half* __restrict__ y2T,
    const ushort* __restrict__ qw3, const float* __restrict__ sc3, const float* __restrict__ bq3,
    const float* __restrict__ x, unsigned* umax, float* __restrict__ out)
{
  __shared__ ushort lds[24*64*8];                // 24576 B (stride-64 addressing)
  int n = blockIdx.x, pc = blockIdx.y, tid = threadIdx.x;
  int w = tid >> 6, l = tid & 63;
  int lhi = l >> 4, llo = l & 15;
  int m0 = w*16;
  int p0 = pc*56;
  uint4* l4 = (uint4*)lds;

  uint4 ld[4];
  // prefetch chunk 0 FIRST (addresses independent of s2)
  #pragma unroll
  for(int i=0;i<4;i++){
    int idx = tid + i*384;
    if(idx < 24*56){
      int cl = idx/56, r = idx - cl*56;
      ld[i] = *(const uint4*)((const ushort*)y2T + ((size_t)(n*72 + cl)*HW + p0 + r)*8);
    }
  }
  float s2 = __uint_as_float(umax[2])/127.f + 1e-8f;
  float r2 = 1.f/s2;
  float scf[4], bf[4];
  #pragma unroll
  for(int r=0;r<4;r++){ int o = m0 + lhi*4 + r; scf[r] = s2*sc3[o]; bf[r] = bq3[o]; }
  floatx4 acc[4];
  #pragma unroll
  for(int f=0;f<4;f++) acc[f] = (floatx4){0.f,0.f,0.f,0.f};

  for(int ck=0; ck<3; ck++){
    if(ck > 0) __syncthreads();                  // prev chunk's MFMA readers done
    // write regs -> LDS, quantizing (reciprocal-mult; q in [0,127])
    #pragma unroll
    for(int i=0;i<4;i++){
      int idx = tid + i*384;
      if(idx < 24*56){
        int cl = idx/56, r = idx - cl*56;
        uint rw[4] = {ld[i].x, ld[i].y, ld[i].z, ld[i].w};
        uint pk[4];
        #pragma unroll
        for(int j=0;j<4;j++){
          float lo = __half2float(__ushort_as_half((ushort)(rw[j] & 0xffffu)));
          float hi = __half2float(__ushort_as_half((ushort)(rw[j] >> 16)));
          uint qlo = (uint)f2bf(rintf(lo * r2));
          uint qhi = (uint)f2bf(rintf(hi * r2));
          pk[j] = (qhi << 16) | qlo;
        }
        l4[cl*64 + r] = (uint4){pk[0], pk[1], pk[2], pk[3]};
      }
    }
    if(ck < 2){                                  // issue next chunk's loads NOW
      #pragma unroll
      for(int i=0;i<4;i++){
        int idx = tid + i*384;
        if(idx < 24*56){
          int cl = idx/56, r = idx - cl*56;
          ld[i] = *(const uint4*)((const ushort*)y2T + ((size_t)(n*72 + (ck+1)*24 + cl)*HW + p0 + r)*8);
        }
      }
    }
    __syncthreads();                             // LDS visible
    #pragma unroll
    for(int ks=0; ks<6; ks++){
      const short8 a = *(const short8*)(qw3 + (m0 + llo)*MIDC + ck*192 + ks*32 + lhi*8);
      #pragma unroll
      for(int f=0; f<4; f++){
        const short8 b = *(const short8*)(lds + ((ks*4 + lhi)*64 + f*16 + llo)*8);
        acc[f] = __builtin_amdgcn_mfma_f32_16x16x32_bf16(a, b, acc[f], 0, 0, 0);
      }
    }
  }
  float tmax = 0.f;
  #pragma unroll
  for(int f=0; f<4; f++){
    if(f*16 + llo < 56){
      #pragma unroll
      for(int r=0;r<4;r++){
        size_t idx = (size_t)(n*COUT + m0 + lhi*4 + r)*HW + p0 + f*16 + llo;
        float v = fmaf(acc[f][r], scf[r], bf[r]) + x[idx];
        tmax = fmaxf(tmax, fabsf(v));
        out[idx] = v;
      }
    }
  }
  block_max_atomic(tmax, umax + 3);
}

// final per-tensor fake-quant of out (in place) + write scale. TRUE division kept here.
__global__ void k_finalq(float* __restrict__ out, const unsigned* __restrict__ umax, float* __restrict__ sf){
  int i = blockIdx.x*256 + threadIdx.x;          // exactly NX/4 threads
  float4* o4 = (float4*)out;
  float4 v = o4[i];                              // load before s3 use
  float s3 = __uint_as_float(umax[3]) / 127.f + 1e-8f;
  v.x = fq(v.x, s3); v.y = fq(v.y, s3); v.z = fq(v.z, s3); v.w = fq(v.w, s3);
  o4[i] = v;
  if(i == 0) *sf = s3;
}

// ---------------- launch ----------------

extern "C" void kernel_launch(void* const* d_in, const int* in_sizes, int n_in,
                              void* d_out, int out_size, void* d_ws, size_t ws_size,
                              hipStream_t stream)
{
  const float* x  = (const float*)d_in[0];
  const float* w1 = (const float*)d_in[1];
  const float* g1 = (const float*)d_in[2];
  const float* b1 = (const float*)d_in[3];
  const float* m1 = (const float*)d_in[4];
  const float* v1 = (const float*)d_in[5];
  const float* w2 = (const float*)d_in[6];
  const float* g2 = (const float*)d_in[7];
  const float* b2 = (const float*)d_in[8];
  const float* m2 = (const float*)d_in[9];
  const float* v2 = (const float*)d_in[10];
  const float* w3 = (const float*)d_in[11];
  const float* g3 = (const float*)d_in[12];
  const float* b3 = (const float*)d_in[13];
  const float* m3 = (const float*)d_in[14];
  const float* v3 = (const float*)d_in[15];

  char* ws = (char*)d_ws;
  unsigned* umax = (unsigned*)(ws + 0);
  float* sc1  = (float*)(ws + 256);
  float* bq1  = (float*)(ws + 2560);
  float* bq2  = (float*)(ws + 4864);
  float* wq2  = (float*)(ws + 7168);
  float* sc3  = (float*)(ws + 27904);
  float* bq3  = (float*)(ws + 28288);
  ushort* qw1 = (ushort*)(ws + 28672);
  ushort* qw3 = (ushort*)(ws + 139264);
  __half* y1T = (__half*)(ws + 9883648);         // fp16 blocked, 57.8 MB
  __half* y2T = (__half*)(ws + 67686400);        // fp16 blocked, 57.8 MB

  float* outp = (float*)d_out;

  hipMemsetAsync(umax, 0, 16, stream);
  k_prep<<<824, 256, 0, stream>>>(w1,g1,b1,m1,v1, w2,g2,b2,m2,v2, w3,g3,b3,m3,v3,
                                  qw1,sc1,bq1, wq2,bq2, qw3,sc3,bq3,
                                  (const float4*)x, umax);
  k_conv1f<<<dim3(64,14), 384, 0, stream>>>(x, qw1, sc1, bq1, umax, y1T);
  k_conv2<<<1152, 256, 0, stream>>>(y1T, wq2, bq2, umax, y2T);
  k_conv3<<<dim3(64,14), 384, 0, stream>>>(y2T, qw3, sc3, bq3, x, umax, outp);
  k_finalq<<<NX/4/256, 256, 0, stream>>>(outp, umax, outp + NX);
}